// Round 4
// baseline (872.771 us; speedup 1.0000x reference)
//
#include <hip/hip_runtime.h>
#include <stdint.h>

#define N_NODES 50000
#define D 128
#define NE 800000

typedef __bf16 bf16x8 __attribute__((ext_vector_type(8)));
typedef float floatx4 __attribute__((ext_vector_type(4)));
typedef unsigned int uint4v __attribute__((ext_vector_type(4)));

__device__ __forceinline__ unsigned short f2bf(float f) {
    unsigned u = __float_as_uint(f);
    u += 0x7fffu + ((u >> 16) & 1u);
    return (unsigned short)(u >> 16);
}
__device__ __forceinline__ float bf2f(unsigned short h) {
    return __uint_as_float(((unsigned)h) << 16);
}
__device__ __forceinline__ bf16x8 ldnt_bf16x8(const unsigned short* p) {
    uint4v v = __builtin_nontemporal_load((const uint4v*)p);
    union { uint4v u; bf16x8 b; } c; c.u = v; return c.b;
}

// ---------------- CSR build ----------------
__global__ void k_hist(const int* __restrict__ dun, const int* __restrict__ dnu,
                       int* deg_n, int* deg_u) {
    int id = blockIdx.x * blockDim.x + threadIdx.x;
    if (id < NE) atomicAdd(&deg_n[dun[id]], 1);
    else if (id < 2 * NE) atomicAdd(&deg_u[dnu[id - NE]], 1);
}

__global__ void k_scan(const int* __restrict__ deg_n, const int* __restrict__ deg_u,
                       int* offs_n, int* offs_u) {
    const int* deg = blockIdx.x ? deg_u : deg_n;
    int* offs = blockIdx.x ? offs_u : offs_n;
    __shared__ int lds[1024];
    int t = threadIdx.x;
    const int CH = (N_NODES + 1023) / 1024;  // 49
    int base = t * CH;
    int end = min(base + CH, N_NODES);
    int s = 0;
    for (int i = base; i < end; ++i) s += deg[i];
    lds[t] = s;
    __syncthreads();
    for (int off = 1; off < 1024; off <<= 1) {
        int v = lds[t];
        int w = (t >= off) ? lds[t - off] : 0;
        __syncthreads();
        lds[t] = v + w;
        __syncthreads();
    }
    int run = lds[t] - s;  // exclusive base
    for (int i = base; i < end; ++i) { offs[i] = run; run += deg[i]; }
    if (t == 1023) offs[N_NODES] = lds[1023];
}

__global__ void k_scatter(const int* __restrict__ sun, const int* __restrict__ dun,
                          const int* __restrict__ snu, const int* __restrict__ dnu,
                          const int* __restrict__ offs_n, const int* __restrict__ offs_u,
                          int* cur_n, int* cur_u, int* srcs_n, int* srcs_u) {
    int id = blockIdx.x * blockDim.x + threadIdx.x;
    if (id < NE) {
        int d = dun[id];
        int p = offs_n[d] + atomicAdd(&cur_n[d], 1);
        srcs_n[p] = sun[id];
    } else if (id < 2 * NE) {
        int e = id - NE;
        int d = dnu[e];
        int p = offs_u[d] + atomicAdd(&cur_u[d], 1);
        srcs_u[p] = snu[e];
    }
}

// ------------- convert x/h fp32 -> bf16 into u3; layout [agg_x|agg_h|x|h] -------------
__global__ void k_conv_xh(const float* __restrict__ xu, const float* __restrict__ hu,
                          const float* __restrict__ xn, const float* __restrict__ hn,
                          unsigned short* u3_u, unsigned short* u3_n) {
    int id = blockIdx.x * blockDim.x + threadIdx.x;
    const int PER = N_NODES * (D / 4);  // 1,600,000
    int arr = id / PER;
    int rem = id - arr * PER;
    int row = rem >> 5;
    int c4 = rem & 31;
    const float* src;
    unsigned short* dst;
    int colbase;
    if (arr == 0)      { src = xu; dst = u3_u; colbase = 256; }
    else if (arr == 1) { src = hu; dst = u3_u; colbase = 384; }
    else if (arr == 2) { src = xn; dst = u3_n; colbase = 256; }
    else               { src = hn; dst = u3_n; colbase = 384; }
    float4 v = *(const float4*)(src + row * D + c4 * 4);
    ushort4 o;
    o.x = f2bf(v.x); o.y = f2bf(v.y); o.z = f2bf(v.z); o.w = f2bf(v.w);
    *(ushort4*)(dst + row * 512 + colbase + c4 * 4) = o;
}

// ------------- weights -> transposed stacked bf16, layout [n][k] -------------
// per type t: [Wz 128x512: Wl0|Wl1|Wr0|Wr1][Wr_ 128x512: Wl2|Wl3|Wr2|Wr3]
//             [Wc 128x256: Wl4|Wr4][Wh 128x256: Wl5|Wr5]
__global__ void k_conv_w(const float* __restrict__ Wl, const float* __restrict__ Wr,
                         unsigned short* wt) {
    int f = blockIdx.x * blockDim.x + threadIdx.x;
    if (f >= 2 * 196608) return;
    int t = f / 196608;
    int o = f - t * 196608;
    int n, k, g;
    const float* W;
    if (o < 131072) {  // z (g0=0) or r (g0=2), K=512
        int g0 = (o < 65536) ? 0 : 2;
        int oo = o & 65535;
        n = oo >> 9; k = oo & 511;
        int seg = k >> 7;
        W = (seg < 2) ? Wl : Wr;
        g = g0 + (seg & 1);
    } else {  // c (g=4) or h (g=5), K=256
        int oo = o - 131072;
        g = (oo < 32768) ? 4 : 5;
        oo &= 32767;
        n = oo >> 8; k = oo & 255;
        int seg = k >> 7;
        W = seg ? Wr : Wl;
    }
    int kk = k & 127;
    wt[f] = f2bf(W[((g * 2 + t) * 128 + kk) * 128 + n]);
}

// ------------- agg2: mean of x,h rows; 2 edge-slots/wave, 16B/lane contiguous 512B/edge ----
__global__ void k_agg2(const int* __restrict__ offs_n, const int* __restrict__ srcs_n,
                       const int* __restrict__ offs_u, const int* __restrict__ srcs_u,
                       const unsigned short* __restrict__ u3_n_ro,
                       const unsigned short* __restrict__ u3_u_ro,
                       unsigned short* u3_n, unsigned short* u3_u) {
    int dir = blockIdx.y;
    int node = blockIdx.x * 4 + (threadIdx.x >> 6);
    int lane = threadIdx.x & 63;
    const int* offs = dir ? offs_u : offs_n;
    const int* srcs = dir ? srcs_u : srcs_n;
    const unsigned short* src_feat = dir ? u3_n_ro : u3_u_ro;
    unsigned short* dst = dir ? u3_u : u3_n;
    int c0 = offs[node], c1 = offs[node + 1];
    int eslot = lane >> 5;   // which edge within a pair
    int sub = lane & 31;     // 16B chunk of the 512B [x|h] run
    int srcoff = 256 + sub * 8;
    float a[8];
#pragma unroll
    for (int i = 0; i < 8; ++i) a[i] = 0.f;
    auto acc8 = [&](uint4 v) {
        a[0] += bf2f(v.x & 0xffff); a[1] += bf2f(v.x >> 16);
        a[2] += bf2f(v.y & 0xffff); a[3] += bf2f(v.y >> 16);
        a[4] += bf2f(v.z & 0xffff); a[5] += bf2f(v.z >> 16);
        a[6] += bf2f(v.w & 0xffff); a[7] += bf2f(v.w >> 16);
    };
    int e = c0 + eslot;
    for (; e + 6 < c1; e += 8) {
        int s0 = srcs[e], s1 = srcs[e + 2], s2 = srcs[e + 4], s3 = srcs[e + 6];
        uint4 v0 = *(const uint4*)(src_feat + (size_t)s0 * 512 + srcoff);
        uint4 v1 = *(const uint4*)(src_feat + (size_t)s1 * 512 + srcoff);
        uint4 v2 = *(const uint4*)(src_feat + (size_t)s2 * 512 + srcoff);
        uint4 v3 = *(const uint4*)(src_feat + (size_t)s3 * 512 + srcoff);
        acc8(v0); acc8(v1); acc8(v2); acc8(v3);
    }
    for (; e < c1; e += 2) {
        uint4 v = *(const uint4*)(src_feat + (size_t)srcs[e] * 512 + srcoff);
        acc8(v);
    }
#pragma unroll
    for (int i = 0; i < 8; ++i) a[i] += __shfl_xor(a[i], 32);
    if (eslot == 0) {
        float inv = 1.f / (float)max(c1 - c0, 1);
        uint4 o;
        o.x = (unsigned)f2bf(a[0] * inv) | ((unsigned)f2bf(a[1] * inv) << 16);
        o.y = (unsigned)f2bf(a[2] * inv) | ((unsigned)f2bf(a[3] * inv) << 16);
        o.z = (unsigned)f2bf(a[4] * inv) | ((unsigned)f2bf(a[5] * inv) << 16);
        o.w = (unsigned)f2bf(a[6] * inv) | ((unsigned)f2bf(a[7] * inv) << 16);
        *(uint4*)(dst + (size_t)node * 512 + sub * 8) = o;
    }
}

// ------------- agg4: mean of s rows; 4 edge-slots/wave, 256B/edge contiguous -------------
__global__ void k_agg4(const int* __restrict__ offs_n, const int* __restrict__ srcs_n,
                       const int* __restrict__ offs_u, const int* __restrict__ srcs_u,
                       const unsigned short* __restrict__ u2_n_ro,
                       const unsigned short* __restrict__ u2_u_ro,
                       unsigned short* u2_n, unsigned short* u2_u) {
    int dir = blockIdx.y;
    int node = blockIdx.x * 4 + (threadIdx.x >> 6);
    int lane = threadIdx.x & 63;
    const int* offs = dir ? offs_u : offs_n;
    const int* srcs = dir ? srcs_u : srcs_n;
    const unsigned short* src_feat = dir ? u2_n_ro : u2_u_ro;
    unsigned short* dst = dir ? u2_u : u2_n;
    int c0 = offs[node], c1 = offs[node + 1];
    int eslot = lane >> 4;   // 0..3
    int sub = lane & 15;     // 16B chunk of the 256B s-run
    int srcoff = 128 + sub * 8;
    float a[8];
#pragma unroll
    for (int i = 0; i < 8; ++i) a[i] = 0.f;
    auto acc8 = [&](uint4 v) {
        a[0] += bf2f(v.x & 0xffff); a[1] += bf2f(v.x >> 16);
        a[2] += bf2f(v.y & 0xffff); a[3] += bf2f(v.y >> 16);
        a[4] += bf2f(v.z & 0xffff); a[5] += bf2f(v.z >> 16);
        a[6] += bf2f(v.w & 0xffff); a[7] += bf2f(v.w >> 16);
    };
    int e = c0 + eslot;
    for (; e + 12 < c1; e += 16) {
        int s0 = srcs[e], s1 = srcs[e + 4], s2 = srcs[e + 8], s3 = srcs[e + 12];
        uint4 v0 = *(const uint4*)(src_feat + (size_t)s0 * 256 + srcoff);
        uint4 v1 = *(const uint4*)(src_feat + (size_t)s1 * 256 + srcoff);
        uint4 v2 = *(const uint4*)(src_feat + (size_t)s2 * 256 + srcoff);
        uint4 v3 = *(const uint4*)(src_feat + (size_t)s3 * 256 + srcoff);
        acc8(v0); acc8(v1); acc8(v2); acc8(v3);
    }
    for (; e < c1; e += 4) {
        uint4 v = *(const uint4*)(src_feat + (size_t)srcs[e] * 256 + srcoff);
        acc8(v);
    }
#pragma unroll
    for (int i = 0; i < 8; ++i) a[i] += __shfl_xor(a[i], 32);
#pragma unroll
    for (int i = 0; i < 8; ++i) a[i] += __shfl_xor(a[i], 16);
    if (eslot == 0) {
        float inv = 1.f / (float)max(c1 - c0, 1);
        uint4 o;
        o.x = (unsigned)f2bf(a[0] * inv) | ((unsigned)f2bf(a[1] * inv) << 16);
        o.y = (unsigned)f2bf(a[2] * inv) | ((unsigned)f2bf(a[3] * inv) << 16);
        o.z = (unsigned)f2bf(a[4] * inv) | ((unsigned)f2bf(a[5] * inv) << 16);
        o.w = (unsigned)f2bf(a[6] * inv) | ((unsigned)f2bf(a[7] * inv) << 16);
        *(uint4*)(dst + (size_t)node * 256 + sub * 8) = o;
    }
}

// ------------- phase 3: z, r, cx via MFMA; M=64/block; nt A-stream keeps B L2-hot -------------
__global__ __launch_bounds__(256) void k_gates(
    const unsigned short* __restrict__ u3_n, const unsigned short* __restrict__ u3_u,
    const unsigned short* __restrict__ wt, const float* __restrict__ bias,
    unsigned short* z_n, unsigned short* z_u,
    unsigned short* cx_n, unsigned short* cx_u,
    unsigned short* u2_n, unsigned short* u2_u) {
    int t = blockIdx.y;  // 0 news, 1 user
    const unsigned short* u3 = t ? u3_u : u3_n;
    unsigned short* zb = t ? z_u : z_n;
    unsigned short* cb = t ? cx_u : cx_n;
    unsigned short* u2 = t ? u2_u : u2_n;
    const unsigned short* wbase = wt + t * 196608;
    const unsigned short* wz = wbase;
    const unsigned short* wr_ = wbase + 65536;
    const unsigned short* wc = wbase + 131072;

    int row0 = blockIdx.x * 64;
    int tid = threadIdx.x;
    int lane = tid & 63;
    int w = tid >> 6;
    int l15 = lane & 15;
    int quad = lane >> 4;
    int cw = w * 32;

    floatx4 zero = {0.f, 0.f, 0.f, 0.f};
    floatx4 accz[4][2], accr[4][2], accc[4][2];
#pragma unroll
    for (int i = 0; i < 4; ++i)
#pragma unroll
        for (int j = 0; j < 2; ++j) { accz[i][j] = zero; accr[i][j] = zero; accc[i][j] = zero; }

    const unsigned short* arow[4];
#pragma unroll
    for (int rt = 0; rt < 4; ++rt) {
        int r = min(row0 + rt * 16 + l15, N_NODES - 1);
        arow[rt] = u3 + (size_t)r * 512;
    }

#pragma unroll
    for (int kt = 0; kt < 16; ++kt) {
        int ko = kt * 32 + quad * 8;
        bf16x8 a[4];
#pragma unroll
        for (int rt = 0; rt < 4; ++rt) a[rt] = ldnt_bf16x8(arow[rt] + ko);
#pragma unroll
        for (int ct = 0; ct < 2; ++ct) {
            int colg = cw + ct * 16 + l15;
            bf16x8 bz = *(const bf16x8*)(wz + colg * 512 + ko);
#pragma unroll
            for (int rt = 0; rt < 4; ++rt)
                accz[rt][ct] = __builtin_amdgcn_mfma_f32_16x16x32_bf16(a[rt], bz, accz[rt][ct], 0, 0, 0);
            bf16x8 br = *(const bf16x8*)(wr_ + colg * 512 + ko);
#pragma unroll
            for (int rt = 0; rt < 4; ++rt)
                accr[rt][ct] = __builtin_amdgcn_mfma_f32_16x16x32_bf16(a[rt], br, accr[rt][ct], 0, 0, 0);
            // c-gate: A k-ranges [agg_x: kt 0..3] and [x: kt 8..11]
            if (kt < 4 || (kt >= 8 && kt < 12)) {
                int kc = (kt < 4) ? kt : (kt - 4);
                bf16x8 bc = *(const bf16x8*)(wc + colg * 256 + kc * 32 + quad * 8);
#pragma unroll
                for (int rt = 0; rt < 4; ++rt)
                    accc[rt][ct] = __builtin_amdgcn_mfma_f32_16x16x32_bf16(a[rt], bc, accc[rt][ct], 0, 0, 0);
            }
        }
    }

#pragma unroll
    for (int ct = 0; ct < 2; ++ct) {
        int col = cw + ct * 16 + l15;
        float bz_ = bias[(0 * 2 + t) * 128 + col] + bias[(1 * 2 + t) * 128 + col];
        float br_ = bias[(2 * 2 + t) * 128 + col] + bias[(3 * 2 + t) * 128 + col];
        float bc_ = bias[(4 * 2 + t) * 128 + col];
#pragma unroll
        for (int rt = 0; rt < 4; ++rt) {
#pragma unroll
            for (int v = 0; v < 4; ++v) {
                int row = row0 + rt * 16 + quad * 4 + v;
                if (row < N_NODES) {
                    float zv = 1.f / (1.f + __expf(-(accz[rt][ct][v] + bz_)));
                    float rv = 1.f / (1.f + __expf(-(accr[rt][ct][v] + br_)));
                    float cv = accc[rt][ct][v] + bc_;
                    float hv = bf2f(__builtin_nontemporal_load(u3 + (size_t)row * 512 + 384 + col));
                    __builtin_nontemporal_store(f2bf(zv), zb + (size_t)row * 128 + col);
                    __builtin_nontemporal_store(f2bf(cv), cb + (size_t)row * 128 + col);
                    __builtin_nontemporal_store(f2bf(hv * rv), u2 + (size_t)row * 256 + 128 + col);
                }
            }
        }
    }
}

// ------------- phase 5: ht = tanh(cx + [agg_s|s]@Wh + b5); h' = z*h + (1-z)*ht -------------
__global__ __launch_bounds__(256) void k_out(
    const unsigned short* __restrict__ u2_n, const unsigned short* __restrict__ u2_u,
    const unsigned short* __restrict__ u3_n, const unsigned short* __restrict__ u3_u,
    const unsigned short* __restrict__ wt, const float* __restrict__ bias,
    const unsigned short* __restrict__ z_n, const unsigned short* __restrict__ z_u,
    const unsigned short* __restrict__ cx_n, const unsigned short* __restrict__ cx_u,
    float* out) {
    int t = blockIdx.y;
    const unsigned short* u2 = t ? u2_u : u2_n;
    const unsigned short* u3 = t ? u3_u : u3_n;
    const unsigned short* zb = t ? z_u : z_n;
    const unsigned short* cb = t ? cx_u : cx_n;
    float* op = out + (t ? 0 : (size_t)N_NODES * D);  // output order: h_user first
    const unsigned short* wh = wt + t * 196608 + 163840;

    int row0 = blockIdx.x * 64;
    int tid = threadIdx.x;
    int lane = tid & 63;
    int w = tid >> 6;
    int l15 = lane & 15;
    int quad = lane >> 4;
    int cw = w * 32;

    floatx4 zero = {0.f, 0.f, 0.f, 0.f};
    floatx4 acc[4][2];
#pragma unroll
    for (int i = 0; i < 4; ++i)
#pragma unroll
        for (int j = 0; j < 2; ++j) acc[i][j] = zero;

    const unsigned short* arow[4];
#pragma unroll
    for (int rt = 0; rt < 4; ++rt) {
        int r = min(row0 + rt * 16 + l15, N_NODES - 1);
        arow[rt] = u2 + (size_t)r * 256;
    }

#pragma unroll
    for (int kt = 0; kt < 8; ++kt) {
        int ko = kt * 32 + quad * 8;
        bf16x8 a[4];
#pragma unroll
        for (int rt = 0; rt < 4; ++rt) a[rt] = ldnt_bf16x8(arow[rt] + ko);
#pragma unroll
        for (int ct = 0; ct < 2; ++ct) {
            int colg = cw + ct * 16 + l15;
            bf16x8 b = *(const bf16x8*)(wh + colg * 256 + ko);
#pragma unroll
            for (int rt = 0; rt < 4; ++rt)
                acc[rt][ct] = __builtin_amdgcn_mfma_f32_16x16x32_bf16(a[rt], b, acc[rt][ct], 0, 0, 0);
        }
    }

#pragma unroll
    for (int ct = 0; ct < 2; ++ct) {
        int col = cw + ct * 16 + l15;
        float bh_ = bias[(5 * 2 + t) * 128 + col];
#pragma unroll
        for (int rt = 0; rt < 4; ++rt) {
#pragma unroll
            for (int v = 0; v < 4; ++v) {
                int row = row0 + rt * 16 + quad * 4 + v;
                if (row < N_NODES) {
                    float cx = bf2f(__builtin_nontemporal_load(cb + (size_t)row * 128 + col));
                    float x = cx + acc[rt][ct][v] + bh_;
                    x = fminf(fmaxf(x, -15.f), 15.f);
                    float e = __expf(2.f * x);
                    float ht = (e - 1.f) / (e + 1.f);
                    float zv = bf2f(__builtin_nontemporal_load(zb + (size_t)row * 128 + col));
                    float hv = bf2f(__builtin_nontemporal_load(u3 + (size_t)row * 512 + 384 + col));
                    __builtin_nontemporal_store(zv * hv + (1.f - zv) * ht,
                                                op + (size_t)row * 128 + col);
                }
            }
        }
    }
}

extern "C" void kernel_launch(void* const* d_in, const int* in_sizes, int n_in,
                              void* d_out, int out_size, void* d_ws, size_t ws_size,
                              hipStream_t stream) {
    const float* xu = (const float*)d_in[0];
    const float* xn = (const float*)d_in[1];
    const float* hu = (const float*)d_in[2];
    const float* hn = (const float*)d_in[3];
    const float* Wl = (const float*)d_in[4];
    const float* Wr = (const float*)d_in[5];
    const float* b  = (const float*)d_in[6];
    const int* sun = (const int*)d_in[7];
    const int* dun = (const int*)d_in[8];
    const int* snu = (const int*)d_in[9];
    const int* dnu = (const int*)d_in[10];
    float* out = (float*)d_out;

    char* ws = (char*)d_ws;
    size_t off = 0;
    auto alloc = [&](size_t bytes) -> void* {
        void* p = ws + off;
        off += (bytes + 255) & ~(size_t)255;
        return p;
    };
    unsigned short* wt = (unsigned short*)alloc((size_t)2 * 196608 * 2);
    int* zeros = (int*)alloc((size_t)4 * N_NODES * 4);  // deg_n, deg_u, cur_n, cur_u
    int* deg_n = zeros;
    int* deg_u = zeros + N_NODES;
    int* cur_n = zeros + 2 * N_NODES;
    int* cur_u = zeros + 3 * N_NODES;
    int* offs_n = (int*)alloc((size_t)(N_NODES + 1) * 4);
    int* offs_u = (int*)alloc((size_t)(N_NODES + 1) * 4);
    int* srcs_n = (int*)alloc((size_t)NE * 4);
    int* srcs_u = (int*)alloc((size_t)NE * 4);
    unsigned short* u3_n = (unsigned short*)alloc((size_t)N_NODES * 512 * 2);
    unsigned short* u3_u = (unsigned short*)alloc((size_t)N_NODES * 512 * 2);
    unsigned short* u2_n = (unsigned short*)alloc((size_t)N_NODES * 256 * 2);
    unsigned short* u2_u = (unsigned short*)alloc((size_t)N_NODES * 256 * 2);
    unsigned short* z_n  = (unsigned short*)alloc((size_t)N_NODES * 128 * 2);
    unsigned short* z_u  = (unsigned short*)alloc((size_t)N_NODES * 128 * 2);
    unsigned short* cx_n = (unsigned short*)alloc((size_t)N_NODES * 128 * 2);
    unsigned short* cx_u = (unsigned short*)alloc((size_t)N_NODES * 128 * 2);
    (void)in_sizes; (void)n_in; (void)out_size; (void)ws_size;

    (void)hipMemsetAsync(zeros, 0, (size_t)4 * N_NODES * 4, stream);
    k_hist<<<(2 * NE + 255) / 256, 256, 0, stream>>>(dun, dnu, deg_n, deg_u);
    k_scan<<<2, 1024, 0, stream>>>(deg_n, deg_u, offs_n, offs_u);
    k_scatter<<<(2 * NE + 255) / 256, 256, 0, stream>>>(sun, dun, snu, dnu, offs_n, offs_u,
                                                        cur_n, cur_u, srcs_n, srcs_u);
    k_conv_xh<<<(4 * N_NODES * (D / 4)) / 256, 256, 0, stream>>>(xu, hu, xn, hn, u3_u, u3_n);
    k_conv_w<<<(2 * 196608 + 255) / 256, 256, 0, stream>>>(Wl, Wr, wt);
    k_agg2<<<dim3(N_NODES / 4, 2), 256, 0, stream>>>(offs_n, srcs_n, offs_u, srcs_u,
                                                     u3_n, u3_u, u3_n, u3_u);
    k_gates<<<dim3((N_NODES + 63) / 64, 2), 256, 0, stream>>>(u3_n, u3_u, wt, b,
                                                              z_n, z_u, cx_n, cx_u, u2_n, u2_u);
    k_agg4<<<dim3(N_NODES / 4, 2), 256, 0, stream>>>(offs_n, srcs_n, offs_u, srcs_u,
                                                     u2_n, u2_u, u2_n, u2_u);
    k_out<<<dim3((N_NODES + 63) / 64, 2), 256, 0, stream>>>(u2_n, u2_u, u3_n, u3_u, wt, b,
                                                            z_n, z_u, cx_n, cx_u, out);
}

// Round 5
// 725.460 us; speedup vs baseline: 1.2031x; 1.2031x over previous
//
#include <hip/hip_runtime.h>
#include <stdint.h>

#define N_NODES 50000
#define D 128
#define NE 800000

typedef __bf16 bf16x8 __attribute__((ext_vector_type(8)));
typedef float floatx4 __attribute__((ext_vector_type(4)));

__device__ __forceinline__ unsigned short f2bf(float f) {
    unsigned u = __float_as_uint(f);
    u += 0x7fffu + ((u >> 16) & 1u);
    return (unsigned short)(u >> 16);
}
__device__ __forceinline__ float bf2f(unsigned short h) {
    return __uint_as_float(((unsigned)h) << 16);
}
__device__ __forceinline__ void dma_lds_16(const unsigned short* g, unsigned short* l) {
    // each lane copies 16B: global g+lane*8 elems -> LDS l+lane*8 elems (contiguous 1KB/wave)
    int lane = threadIdx.x & 63;
    __builtin_amdgcn_global_load_lds(
        (const __attribute__((address_space(1))) void*)(g + lane * 8),
        (__attribute__((address_space(3))) void*)(l + lane * 8), 16, 0, 0);
}

// ---------------- CSR build ----------------
__global__ void k_hist(const int* __restrict__ dun, const int* __restrict__ dnu,
                       int* deg_n, int* deg_u) {
    int id = blockIdx.x * blockDim.x + threadIdx.x;
    if (id < NE) atomicAdd(&deg_n[dun[id]], 1);
    else if (id < 2 * NE) atomicAdd(&deg_u[dnu[id - NE]], 1);
}

__global__ void k_scan(const int* __restrict__ deg_n, const int* __restrict__ deg_u,
                       int* offs_n, int* offs_u) {
    const int* deg = blockIdx.x ? deg_u : deg_n;
    int* offs = blockIdx.x ? offs_u : offs_n;
    __shared__ int lds[1024];
    int t = threadIdx.x;
    const int CH = (N_NODES + 1023) / 1024;  // 49
    int base = t * CH;
    int end = min(base + CH, N_NODES);
    int s = 0;
    for (int i = base; i < end; ++i) s += deg[i];
    lds[t] = s;
    __syncthreads();
    for (int off = 1; off < 1024; off <<= 1) {
        int v = lds[t];
        int w = (t >= off) ? lds[t - off] : 0;
        __syncthreads();
        lds[t] = v + w;
        __syncthreads();
    }
    int run = lds[t] - s;  // exclusive base
    for (int i = base; i < end; ++i) { offs[i] = run; run += deg[i]; }
    if (t == 1023) offs[N_NODES] = lds[1023];
}

__global__ void k_scatter(const int* __restrict__ sun, const int* __restrict__ dun,
                          const int* __restrict__ snu, const int* __restrict__ dnu,
                          const int* __restrict__ offs_n, const int* __restrict__ offs_u,
                          int* cur_n, int* cur_u, int* srcs_n, int* srcs_u) {
    int id = blockIdx.x * blockDim.x + threadIdx.x;
    if (id < NE) {
        int d = dun[id];
        int p = offs_n[d] + atomicAdd(&cur_n[d], 1);
        srcs_n[p] = sun[id];
    } else if (id < 2 * NE) {
        int e = id - NE;
        int d = dnu[e];
        int p = offs_u[d] + atomicAdd(&cur_u[d], 1);
        srcs_u[p] = snu[e];
    }
}

// ------------- convert x/h fp32 -> bf16 into u3; layout [agg_x|agg_h|x|h] -------------
__global__ void k_conv_xh(const float* __restrict__ xu, const float* __restrict__ hu,
                          const float* __restrict__ xn, const float* __restrict__ hn,
                          unsigned short* u3_u, unsigned short* u3_n) {
    int id = blockIdx.x * blockDim.x + threadIdx.x;
    const int PER = N_NODES * (D / 4);  // 1,600,000
    int arr = id / PER;
    int rem = id - arr * PER;
    int row = rem >> 5;
    int c4 = rem & 31;
    const float* src;
    unsigned short* dst;
    int colbase;
    if (arr == 0)      { src = xu; dst = u3_u; colbase = 256; }
    else if (arr == 1) { src = hu; dst = u3_u; colbase = 384; }
    else if (arr == 2) { src = xn; dst = u3_n; colbase = 256; }
    else               { src = hn; dst = u3_n; colbase = 384; }
    float4 v = *(const float4*)(src + row * D + c4 * 4);
    ushort4 o;
    o.x = f2bf(v.x); o.y = f2bf(v.y); o.z = f2bf(v.z); o.w = f2bf(v.w);
    *(ushort4*)(dst + row * 512 + colbase + c4 * 4) = o;
}

// ------------- weights -> transposed stacked bf16, layout [n][k] -------------
// per type t: [Wz 128x512: Wl0|Wl1|Wr0|Wr1][Wr_ 128x512: Wl2|Wl3|Wr2|Wr3]
//             [Wc 128x256: Wl4|Wr4][Wh 128x256: Wl5|Wr5]
__global__ void k_conv_w(const float* __restrict__ Wl, const float* __restrict__ Wr,
                         unsigned short* wt) {
    int f = blockIdx.x * blockDim.x + threadIdx.x;
    if (f >= 2 * 196608) return;
    int t = f / 196608;
    int o = f - t * 196608;
    int n, k, g;
    const float* W;
    if (o < 131072) {  // z (g0=0) or r (g0=2), K=512
        int g0 = (o < 65536) ? 0 : 2;
        int oo = o & 65535;
        n = oo >> 9; k = oo & 511;
        int seg = k >> 7;
        W = (seg < 2) ? Wl : Wr;
        g = g0 + (seg & 1);
    } else {  // c (g=4) or h (g=5), K=256
        int oo = o - 131072;
        g = (oo < 32768) ? 4 : 5;
        oo &= 32767;
        n = oo >> 8; k = oo & 255;
        int seg = k >> 7;
        W = seg ? Wr : Wl;
    }
    int kk = k & 127;
    wt[f] = f2bf(W[((g * 2 + t) * 128 + kk) * 128 + n]);
}

// ------------- agg2: mean of x,h rows; 2 edge-slots/wave, 16B/lane contiguous 512B/edge ----
__global__ void k_agg2(const int* __restrict__ offs_n, const int* __restrict__ srcs_n,
                       const int* __restrict__ offs_u, const int* __restrict__ srcs_u,
                       const unsigned short* __restrict__ u3_n_ro,
                       const unsigned short* __restrict__ u3_u_ro,
                       unsigned short* u3_n, unsigned short* u3_u) {
    int dir = blockIdx.y;
    int node = blockIdx.x * 4 + (threadIdx.x >> 6);
    int lane = threadIdx.x & 63;
    const int* offs = dir ? offs_u : offs_n;
    const int* srcs = dir ? srcs_u : srcs_n;
    const unsigned short* src_feat = dir ? u3_n_ro : u3_u_ro;
    unsigned short* dst = dir ? u3_u : u3_n;
    int c0 = offs[node], c1 = offs[node + 1];
    int eslot = lane >> 5;   // which edge within a pair
    int sub = lane & 31;     // 16B chunk of the 512B [x|h] run
    int srcoff = 256 + sub * 8;
    float a[8];
#pragma unroll
    for (int i = 0; i < 8; ++i) a[i] = 0.f;
    auto acc8 = [&](uint4 v) {
        a[0] += bf2f(v.x & 0xffff); a[1] += bf2f(v.x >> 16);
        a[2] += bf2f(v.y & 0xffff); a[3] += bf2f(v.y >> 16);
        a[4] += bf2f(v.z & 0xffff); a[5] += bf2f(v.z >> 16);
        a[6] += bf2f(v.w & 0xffff); a[7] += bf2f(v.w >> 16);
    };
    int e = c0 + eslot;
    for (; e + 6 < c1; e += 8) {
        int s0 = srcs[e], s1 = srcs[e + 2], s2 = srcs[e + 4], s3 = srcs[e + 6];
        uint4 v0 = *(const uint4*)(src_feat + (size_t)s0 * 512 + srcoff);
        uint4 v1 = *(const uint4*)(src_feat + (size_t)s1 * 512 + srcoff);
        uint4 v2 = *(const uint4*)(src_feat + (size_t)s2 * 512 + srcoff);
        uint4 v3 = *(const uint4*)(src_feat + (size_t)s3 * 512 + srcoff);
        acc8(v0); acc8(v1); acc8(v2); acc8(v3);
    }
    for (; e < c1; e += 2) {
        uint4 v = *(const uint4*)(src_feat + (size_t)srcs[e] * 512 + srcoff);
        acc8(v);
    }
#pragma unroll
    for (int i = 0; i < 8; ++i) a[i] += __shfl_xor(a[i], 32);
    if (eslot == 0) {
        float inv = 1.f / (float)max(c1 - c0, 1);
        uint4 o;
        o.x = (unsigned)f2bf(a[0] * inv) | ((unsigned)f2bf(a[1] * inv) << 16);
        o.y = (unsigned)f2bf(a[2] * inv) | ((unsigned)f2bf(a[3] * inv) << 16);
        o.z = (unsigned)f2bf(a[4] * inv) | ((unsigned)f2bf(a[5] * inv) << 16);
        o.w = (unsigned)f2bf(a[6] * inv) | ((unsigned)f2bf(a[7] * inv) << 16);
        *(uint4*)(dst + (size_t)node * 512 + sub * 8) = o;
    }
}

// ------------- agg4: mean of s rows; 4 edge-slots/wave, 256B/edge contiguous -------------
__global__ void k_agg4(const int* __restrict__ offs_n, const int* __restrict__ srcs_n,
                       const int* __restrict__ offs_u, const int* __restrict__ srcs_u,
                       const unsigned short* __restrict__ u2_n_ro,
                       const unsigned short* __restrict__ u2_u_ro,
                       unsigned short* u2_n, unsigned short* u2_u) {
    int dir = blockIdx.y;
    int node = blockIdx.x * 4 + (threadIdx.x >> 6);
    int lane = threadIdx.x & 63;
    const int* offs = dir ? offs_u : offs_n;
    const int* srcs = dir ? srcs_u : srcs_n;
    const unsigned short* src_feat = dir ? u2_n_ro : u2_u_ro;
    unsigned short* dst = dir ? u2_u : u2_n;
    int c0 = offs[node], c1 = offs[node + 1];
    int eslot = lane >> 4;   // 0..3
    int sub = lane & 15;     // 16B chunk of the 256B s-run
    int srcoff = 128 + sub * 8;
    float a[8];
#pragma unroll
    for (int i = 0; i < 8; ++i) a[i] = 0.f;
    auto acc8 = [&](uint4 v) {
        a[0] += bf2f(v.x & 0xffff); a[1] += bf2f(v.x >> 16);
        a[2] += bf2f(v.y & 0xffff); a[3] += bf2f(v.y >> 16);
        a[4] += bf2f(v.z & 0xffff); a[5] += bf2f(v.z >> 16);
        a[6] += bf2f(v.w & 0xffff); a[7] += bf2f(v.w >> 16);
    };
    int e = c0 + eslot;
    for (; e + 12 < c1; e += 16) {
        int s0 = srcs[e], s1 = srcs[e + 4], s2 = srcs[e + 8], s3 = srcs[e + 12];
        uint4 v0 = *(const uint4*)(src_feat + (size_t)s0 * 256 + srcoff);
        uint4 v1 = *(const uint4*)(src_feat + (size_t)s1 * 256 + srcoff);
        uint4 v2 = *(const uint4*)(src_feat + (size_t)s2 * 256 + srcoff);
        uint4 v3 = *(const uint4*)(src_feat + (size_t)s3 * 256 + srcoff);
        acc8(v0); acc8(v1); acc8(v2); acc8(v3);
    }
    for (; e < c1; e += 4) {
        uint4 v = *(const uint4*)(src_feat + (size_t)srcs[e] * 256 + srcoff);
        acc8(v);
    }
#pragma unroll
    for (int i = 0; i < 8; ++i) a[i] += __shfl_xor(a[i], 32);
#pragma unroll
    for (int i = 0; i < 8; ++i) a[i] += __shfl_xor(a[i], 16);
    if (eslot == 0) {
        float inv = 1.f / (float)max(c1 - c0, 1);
        uint4 o;
        o.x = (unsigned)f2bf(a[0] * inv) | ((unsigned)f2bf(a[1] * inv) << 16);
        o.y = (unsigned)f2bf(a[2] * inv) | ((unsigned)f2bf(a[3] * inv) << 16);
        o.z = (unsigned)f2bf(a[4] * inv) | ((unsigned)f2bf(a[5] * inv) << 16);
        o.w = (unsigned)f2bf(a[6] * inv) | ((unsigned)f2bf(a[7] * inv) << 16);
        *(uint4*)(dst + (size_t)node * 256 + sub * 8) = o;
    }
}

// ------------- phase 3: z, r, cx via MFMA; A staged to LDS via global_load_lds -------------
// LDS: 64 rows, stride 520 ushorts (1040B) -> ds_read_b128 bank = 4*(l15+quad) mod 32 (<=2-way)
#define GSTRIDE 520
__global__ __launch_bounds__(256) void k_gates(
    const unsigned short* __restrict__ u3_n, const unsigned short* __restrict__ u3_u,
    const unsigned short* __restrict__ wt, const float* __restrict__ bias,
    unsigned short* z_n, unsigned short* z_u,
    unsigned short* cx_n, unsigned short* cx_u,
    unsigned short* u2_n, unsigned short* u2_u) {
    extern __shared__ unsigned short lds[];
    int t = blockIdx.y;  // 0 news, 1 user
    const unsigned short* u3 = t ? u3_u : u3_n;
    unsigned short* zb = t ? z_u : z_n;
    unsigned short* cb = t ? cx_u : cx_n;
    unsigned short* u2 = t ? u2_u : u2_n;
    const unsigned short* wbase = wt + t * 196608;
    const unsigned short* wz = wbase;
    const unsigned short* wr_ = wbase + 65536;
    const unsigned short* wc = wbase + 131072;

    int row0 = blockIdx.x * 64;
    int tid = threadIdx.x;
    int lane = tid & 63;
    int w = tid >> 6;
    int l15 = lane & 15;
    int quad = lane >> 4;
    int cw = w * 32;

    // stage A: wave w DMAs rows w*16 .. w*16+15 (1KB each)
#pragma unroll
    for (int i = 0; i < 16; ++i) {
        int rl = w * 16 + i;
        int r = min(row0 + rl, N_NODES - 1);
        dma_lds_16(u3 + (size_t)r * 512, lds + rl * GSTRIDE);
    }
    __syncthreads();

    floatx4 zero = {0.f, 0.f, 0.f, 0.f};
    floatx4 accz[4][2], accr[4][2], accc[4][2];
#pragma unroll
    for (int i = 0; i < 4; ++i)
#pragma unroll
        for (int j = 0; j < 2; ++j) { accz[i][j] = zero; accr[i][j] = zero; accc[i][j] = zero; }

#pragma unroll
    for (int kt = 0; kt < 16; ++kt) {
        int ko = kt * 32 + quad * 8;
        bf16x8 a[4];
#pragma unroll
        for (int rt = 0; rt < 4; ++rt)
            a[rt] = *(const bf16x8*)(lds + (rt * 16 + l15) * GSTRIDE + ko);
#pragma unroll
        for (int ct = 0; ct < 2; ++ct) {
            int colg = cw + ct * 16 + l15;
            bf16x8 bz = *(const bf16x8*)(wz + colg * 512 + ko);
#pragma unroll
            for (int rt = 0; rt < 4; ++rt)
                accz[rt][ct] = __builtin_amdgcn_mfma_f32_16x16x32_bf16(a[rt], bz, accz[rt][ct], 0, 0, 0);
            bf16x8 br = *(const bf16x8*)(wr_ + colg * 512 + ko);
#pragma unroll
            for (int rt = 0; rt < 4; ++rt)
                accr[rt][ct] = __builtin_amdgcn_mfma_f32_16x16x32_bf16(a[rt], br, accr[rt][ct], 0, 0, 0);
            // c-gate: A k-ranges [agg_x: kt 0..3] and [x: kt 8..11]
            if (kt < 4 || (kt >= 8 && kt < 12)) {
                int kc = (kt < 4) ? kt : (kt - 4);
                bf16x8 bc = *(const bf16x8*)(wc + colg * 256 + kc * 32 + quad * 8);
#pragma unroll
                for (int rt = 0; rt < 4; ++rt)
                    accc[rt][ct] = __builtin_amdgcn_mfma_f32_16x16x32_bf16(a[rt], bc, accc[rt][ct], 0, 0, 0);
            }
        }
    }

#pragma unroll
    for (int ct = 0; ct < 2; ++ct) {
        int col = cw + ct * 16 + l15;
        float bz_ = bias[(0 * 2 + t) * 128 + col] + bias[(1 * 2 + t) * 128 + col];
        float br_ = bias[(2 * 2 + t) * 128 + col] + bias[(3 * 2 + t) * 128 + col];
        float bc_ = bias[(4 * 2 + t) * 128 + col];
#pragma unroll
        for (int rt = 0; rt < 4; ++rt) {
#pragma unroll
            for (int v = 0; v < 4; ++v) {
                int rl = rt * 16 + quad * 4 + v;
                int row = row0 + rl;
                if (row < N_NODES) {
                    float zv = 1.f / (1.f + __expf(-(accz[rt][ct][v] + bz_)));
                    float rv = 1.f / (1.f + __expf(-(accr[rt][ct][v] + br_)));
                    float cv = accc[rt][ct][v] + bc_;
                    float hv = bf2f(lds[rl * GSTRIDE + 384 + col]);  // h is staged in LDS
                    zb[(size_t)row * 128 + col] = f2bf(zv);
                    cb[(size_t)row * 128 + col] = f2bf(cv);
                    u2[(size_t)row * 256 + 128 + col] = f2bf(hv * rv);
                }
            }
        }
    }
}

// ------------- phase 5: ht = tanh(cx + [agg_s|s]@Wh + b5); h' = z*h + (1-z)*ht -------------
// LDS: rows paired (1024B contiguous per DMA), pair stride 528 ushorts*2 = 1056B
__global__ __launch_bounds__(256) void k_out(
    const unsigned short* __restrict__ u2_n, const unsigned short* __restrict__ u2_u,
    const unsigned short* __restrict__ u3_n, const unsigned short* __restrict__ u3_u,
    const unsigned short* __restrict__ wt, const float* __restrict__ bias,
    const unsigned short* __restrict__ z_n, const unsigned short* __restrict__ z_u,
    const unsigned short* __restrict__ cx_n, const unsigned short* __restrict__ cx_u,
    float* out) {
    extern __shared__ unsigned short lds[];
    int t = blockIdx.y;
    const unsigned short* u2 = t ? u2_u : u2_n;
    const unsigned short* u3 = t ? u3_u : u3_n;
    const unsigned short* zb = t ? z_u : z_n;
    const unsigned short* cb = t ? cx_u : cx_n;
    float* op = out + (t ? 0 : (size_t)N_NODES * D);  // output order: h_user first
    const unsigned short* wh = wt + t * 196608 + 163840;

    int row0 = blockIdx.x * 64;
    int tid = threadIdx.x;
    int lane = tid & 63;
    int w = tid >> 6;
    int l15 = lane & 15;
    int quad = lane >> 4;
    int cw = w * 32;

    // stage A: wave w DMAs pairs w*8 .. w*8+7 (1KB each = 2 rows)
#pragma unroll
    for (int i = 0; i < 8; ++i) {
        int pl = w * 8 + i;                       // local pair 0..31
        int pr = min(row0 + pl * 2, N_NODES - 2); // N_NODES even
        dma_lds_16(u2 + (size_t)pr * 256, lds + pl * 528);
    }
    __syncthreads();

    floatx4 zero = {0.f, 0.f, 0.f, 0.f};
    floatx4 acc[4][2];
#pragma unroll
    for (int i = 0; i < 4; ++i)
#pragma unroll
        for (int j = 0; j < 2; ++j) acc[i][j] = zero;

#pragma unroll
    for (int kt = 0; kt < 8; ++kt) {
        int ko = kt * 32 + quad * 8;
        bf16x8 a[4];
#pragma unroll
        for (int rt = 0; rt < 4; ++rt) {
            int rl = rt * 16 + l15;
            a[rt] = *(const bf16x8*)(lds + (rl >> 1) * 528 + (rl & 1) * 256 + ko);
        }
#pragma unroll
        for (int ct = 0; ct < 2; ++ct) {
            int colg = cw + ct * 16 + l15;
            bf16x8 b = *(const bf16x8*)(wh + colg * 256 + ko);
#pragma unroll
            for (int rt = 0; rt < 4; ++rt)
                acc[rt][ct] = __builtin_amdgcn_mfma_f32_16x16x32_bf16(a[rt], b, acc[rt][ct], 0, 0, 0);
        }
    }

#pragma unroll
    for (int ct = 0; ct < 2; ++ct) {
        int col = cw + ct * 16 + l15;
        float bh_ = bias[(5 * 2 + t) * 128 + col];
#pragma unroll
        for (int rt = 0; rt < 4; ++rt) {
#pragma unroll
            for (int v = 0; v < 4; ++v) {
                int row = row0 + rt * 16 + quad * 4 + v;
                if (row < N_NODES) {
                    float x = bf2f(cb[(size_t)row * 128 + col]) + acc[rt][ct][v] + bh_;
                    x = fminf(fmaxf(x, -15.f), 15.f);
                    float e = __expf(2.f * x);
                    float ht = (e - 1.f) / (e + 1.f);
                    float zv = bf2f(zb[(size_t)row * 128 + col]);
                    float hv = bf2f(u3[(size_t)row * 512 + 384 + col]);
                    op[(size_t)row * 128 + col] = zv * hv + (1.f - zv) * ht;
                }
            }
        }
    }
}

extern "C" void kernel_launch(void* const* d_in, const int* in_sizes, int n_in,
                              void* d_out, int out_size, void* d_ws, size_t ws_size,
                              hipStream_t stream) {
    const float* xu = (const float*)d_in[0];
    const float* xn = (const float*)d_in[1];
    const float* hu = (const float*)d_in[2];
    const float* hn = (const float*)d_in[3];
    const float* Wl = (const float*)d_in[4];
    const float* Wr = (const float*)d_in[5];
    const float* b  = (const float*)d_in[6];
    const int* sun = (const int*)d_in[7];
    const int* dun = (const int*)d_in[8];
    const int* snu = (const int*)d_in[9];
    const int* dnu = (const int*)d_in[10];
    float* out = (float*)d_out;

    char* ws = (char*)d_ws;
    size_t off = 0;
    auto alloc = [&](size_t bytes) -> void* {
        void* p = ws + off;
        off += (bytes + 255) & ~(size_t)255;
        return p;
    };
    unsigned short* wt = (unsigned short*)alloc((size_t)2 * 196608 * 2);
    int* zeros = (int*)alloc((size_t)4 * N_NODES * 4);  // deg_n, deg_u, cur_n, cur_u
    int* deg_n = zeros;
    int* deg_u = zeros + N_NODES;
    int* cur_n = zeros + 2 * N_NODES;
    int* cur_u = zeros + 3 * N_NODES;
    int* offs_n = (int*)alloc((size_t)(N_NODES + 1) * 4);
    int* offs_u = (int*)alloc((size_t)(N_NODES + 1) * 4);
    int* srcs_n = (int*)alloc((size_t)NE * 4);
    int* srcs_u = (int*)alloc((size_t)NE * 4);
    unsigned short* u3_n = (unsigned short*)alloc((size_t)N_NODES * 512 * 2);
    unsigned short* u3_u = (unsigned short*)alloc((size_t)N_NODES * 512 * 2);
    unsigned short* u2_n = (unsigned short*)alloc((size_t)N_NODES * 256 * 2);
    unsigned short* u2_u = (unsigned short*)alloc((size_t)N_NODES * 256 * 2);
    unsigned short* z_n  = (unsigned short*)alloc((size_t)N_NODES * 128 * 2);
    unsigned short* z_u  = (unsigned short*)alloc((size_t)N_NODES * 128 * 2);
    unsigned short* cx_n = (unsigned short*)alloc((size_t)N_NODES * 128 * 2);
    unsigned short* cx_u = (unsigned short*)alloc((size_t)N_NODES * 128 * 2);
    (void)in_sizes; (void)n_in; (void)out_size; (void)ws_size;

    (void)hipMemsetAsync(zeros, 0, (size_t)4 * N_NODES * 4, stream);
    k_hist<<<(2 * NE + 255) / 256, 256, 0, stream>>>(dun, dnu, deg_n, deg_u);
    k_scan<<<2, 1024, 0, stream>>>(deg_n, deg_u, offs_n, offs_u);
    k_scatter<<<(2 * NE + 255) / 256, 256, 0, stream>>>(sun, dun, snu, dnu, offs_n, offs_u,
                                                        cur_n, cur_u, srcs_n, srcs_u);
    k_conv_xh<<<(4 * N_NODES * (D / 4)) / 256, 256, 0, stream>>>(xu, hu, xn, hn, u3_u, u3_n);
    k_conv_w<<<(2 * 196608 + 255) / 256, 256, 0, stream>>>(Wl, Wr, wt);
    k_agg2<<<dim3(N_NODES / 4, 2), 256, 0, stream>>>(offs_n, srcs_n, offs_u, srcs_u,
                                                     u3_n, u3_u, u3_n, u3_u);
    k_gates<<<dim3((N_NODES + 63) / 64, 2), 256, 64 * GSTRIDE * 2, stream>>>(
        u3_n, u3_u, wt, b, z_n, z_u, cx_n, cx_u, u2_n, u2_u);
    k_agg4<<<dim3(N_NODES / 4, 2), 256, 0, stream>>>(offs_n, srcs_n, offs_u, srcs_u,
                                                     u2_n, u2_u, u2_n, u2_u);
    k_out<<<dim3((N_NODES + 63) / 64, 2), 256, 32 * 528 * 2, stream>>>(
        u2_n, u2_u, u3_n, u3_u, wt, b, z_n, z_u, cx_n, cx_u, out);
}